// Round 5
// baseline (468.849 us; speedup 1.0000x reference)
//
#include <hip/hip_runtime.h>

#define D 4096
#define RANK 1024
#define UELEMS 4194304ULL   // D*RANK
#define NTOT 16777216ULL    // 4^12 = D*D
#define QSCALE 16000.0f

typedef __attribute__((ext_vector_type(4))) int i32x4;

__device__ float g_inv_tr[1];
__device__ float g_scale[D];
__device__ float g_mdre[16];   // M-dagger tables: M†[s][i][j] = conj(M[s][j][i])
__device__ float g_mdim[16];

static __device__ __forceinline__ void load_lds16(const void* g, void* l) {
    __builtin_amdgcn_global_load_lds(
        (const __attribute__((address_space(1))) unsigned int*)g,
        (__attribute__((address_space(3))) unsigned int*)l, 16, 0, 0);
}

#define MFMA_I8 __builtin_amdgcn_mfma_i32_16x16x64_i8

// ---------------------------------------------------------------------------
// i8 split quantization of W = [Ur | Ui] with per-row scale (verified r6).
// ---------------------------------------------------------------------------
__global__ __launch_bounds__(256) void convert_w_i8(const float* __restrict__ P,
                                                    const float* __restrict__ Mre,
                                                    const float* __restrict__ Mim,
                                                    char* __restrict__ Wh,
                                                    char* __restrict__ Wl)
{
    if (blockIdx.x == 0 && threadIdx.x < 16) {
        const int s = threadIdx.x >> 2, i = (threadIdx.x >> 1) & 1, j = threadIdx.x & 1;
        g_mdre[threadIdx.x] =  Mre[s * 4 + j * 2 + i];
        g_mdim[threadIdx.x] = -Mim[s * 4 + j * 2 + i];
    }

    const int w = threadIdx.x >> 6, lane = threadIdx.x & 63;
    const int row = blockIdx.x * 4 + w;

    float ur[16], ui[16];
    const float* pr = P + (size_t)row * RANK + lane * 16;
    const float* pi = P + UELEMS + (size_t)row * RANK + lane * 16;
    #pragma unroll
    for (int q = 0; q < 4; ++q) {
        const float4 a = ((const float4*)pr)[q];
        const float4 b = ((const float4*)pi)[q];
        ur[q * 4 + 0] = a.x; ur[q * 4 + 1] = a.y; ur[q * 4 + 2] = a.z; ur[q * 4 + 3] = a.w;
        ui[q * 4 + 0] = b.x; ui[q * 4 + 1] = b.y; ui[q * 4 + 2] = b.z; ui[q * 4 + 3] = b.w;
    }
    float mx = 0.f;
    #pragma unroll
    for (int e = 0; e < 16; ++e)
        mx = fmaxf(mx, fmaxf(fabsf(ur[e]), fabsf(ui[e])));
    #pragma unroll
    for (int off = 1; off < 64; off <<= 1)
        mx = fmaxf(mx, __shfl_xor(mx, off));
    const float inv = mx > 0.f ? QSCALE / mx : 0.f;
    if (lane == 0) g_scale[row] = mx / QSCALE;

    int hr[16], lr[16], hi[16], li[16];
    #pragma unroll
    for (int e = 0; e < 16; ++e) {
        float q = ur[e] * inv;
        float hf = rintf(q * 0.0078125f);
        hr[e] = (int)hf; lr[e] = (int)rintf(q - 128.f * hf);
        q = ui[e] * inv;
        hf = rintf(q * 0.0078125f);
        hi[e] = (int)hf; li[e] = (int)rintf(q - 128.f * hf);
    }
    uint4 phr, plr, phi, pli;
    unsigned* dst[4] = {(unsigned*)&phr, (unsigned*)&plr, (unsigned*)&phi, (unsigned*)&pli};
    #pragma unroll
    for (int q = 0; q < 4; ++q) {
        unsigned a = 0, b = 0, c = 0, d = 0;
        #pragma unroll
        for (int k = 0; k < 4; ++k) {
            const int sh = k * 8;
            a |= (unsigned)(hr[q * 4 + k] & 255) << sh;
            b |= (unsigned)(lr[q * 4 + k] & 255) << sh;
            c |= (unsigned)(hi[q * 4 + k] & 255) << sh;
            d |= (unsigned)(li[q * 4 + k] & 255) << sh;
        }
        dst[0][q] = a; dst[1][q] = b; dst[2][q] = c; dst[3][q] = d;
    }
    const size_t b1 = (size_t)row * 2048 + lane * 16;
    *(uint4*)&Wh[b1] = phr;          *(uint4*)&Wl[b1] = plr;
    *(uint4*)&Wh[b1 + 1024] = phi;   *(uint4*)&Wl[b1 + 1024] = pli;
}

// ---------------------------------------------------------------------------
// Fused Hermitian GEMM in i8. r15: 64x64 tile, 2 blocks/CU (r14) + REGISTER
// double-buffered fragments + XCD-chunk swizzle.
// r14 post-mortem: MfmaUtil stuck at 37% because each wave's MFMAs depend on
// its own just-issued ds_reads -> every wave lgkm-stalls through the read
// burst (both co-resident blocks in phase). Fix: read kt+1's frags from LDS
// while kt's MFMAs run on regs loaded last half-iteration; the lgkm drain
// lands at the next barrier behind ~1000 cy of MFMA. Frag lifetime: frags for
// buffer X are read one half-iteration BEFORE the barrier that allows X's
// overwrite -> race-free with 2 LDS buffers. Integer acc order unchanged.
// ---------------------------------------------------------------------------
__global__ __launch_bounds__(256, 2) void gemm_rho_i8(const char* __restrict__ Wh,
                                                      const char* __restrict__ Wl,
                                                      float2* __restrict__ rho)
{
    __shared__ __align__(16) char sA[2][4][64 * 64];   // 32768 B
    __shared__ __align__(16) char sB[2][4][64 * 64];   // 32768 B

    // XCD-chunk swizzle: 2080 = 8 * 260 exactly; 260 consecutive triangle
    // tiles per XCD share A-panels -> L2 reuse (cuts the 14x W refetch).
    const int g0 = blockIdx.x;
    const int g = (g0 & 7) * 260 + (g0 >> 3);

    int bi = (int)((sqrtf(8.f * (float)g + 1.f) - 1.f) * 0.5f);
    while (bi * (bi + 1) / 2 > g) --bi;
    while ((bi + 1) * (bi + 2) / 2 <= g) ++bi;
    const int bj = g - bi * (bi + 1) / 2;
    const int row0 = bi << 6, col0 = bj << 6;

    const int t = threadIdx.x;
    const int lane = t & 63, w = t >> 6;
    const int wr = w >> 1, wc = w & 1;          // 2x2 waves of 32x32

    // staging: 64 rows x 64 B per plane; thread t covers row t>>2, slot t&3
    const int ra = t >> 2;
    const int kca = (t & 3) ^ ((ra >> 1) & 3);  // xor-swizzled k-slot
    const size_t aoff = (size_t)(row0 + ra) * 2048 + kca * 16;
    const size_t boff = (size_t)(col0 + ra) * 2048 + kca * 16;
    const int ldso = t * 16;                    // linear LDS dest within plane

    const int m = lane & 15, gq = lane >> 4;
    const int fko = (gq ^ ((m >> 1) & 3)) * 16;

    i32x4 rehh[2][2], remx[2][2], iphh[2][2], ipmx[2][2], iqhh[2][2], iqmx[2][2];
    #pragma unroll
    for (int i = 0; i < 2; ++i)
        #pragma unroll
        for (int j = 0; j < 2; ++j) {
            rehh[i][j] = (i32x4){0, 0, 0, 0}; remx[i][j] = (i32x4){0, 0, 0, 0};
            iphh[i][j] = (i32x4){0, 0, 0, 0}; ipmx[i][j] = (i32x4){0, 0, 0, 0};
            iqhh[i][j] = (i32x4){0, 0, 0, 0}; iqmx[i][j] = (i32x4){0, 0, 0, 0};
        }

    char* const sA0 = &sA[0][0][0];
    char* const sB0 = &sB[0][0][0];

#define STAGE(bn, kt)                                                         \
    {                                                                         \
        const size_t ko_ = (size_t)(kt) * 64;                                 \
        char* dA_ = sA0 + (bn) * 16384;                                       \
        char* dB_ = sB0 + (bn) * 16384;                                       \
        load_lds16(Wh + aoff + ko_,        dA_ + ldso);                       \
        load_lds16(Wl + aoff + ko_,        dA_ + 4096  + ldso);               \
        load_lds16(Wh + aoff + ko_ + 1024, dA_ + 8192  + ldso);               \
        load_lds16(Wl + aoff + ko_ + 1024, dA_ + 12288 + ldso);               \
        load_lds16(Wh + boff + ko_,        dB_ + ldso);                       \
        load_lds16(Wl + boff + ko_,        dB_ + 4096  + ldso);               \
        load_lds16(Wh + boff + ko_ + 1024, dB_ + 8192  + ldso);               \
        load_lds16(Wl + boff + ko_ + 1024, dB_ + 12288 + ldso);               \
    }

#define READ_FRAGS(P, bn)                                                     \
    {                                                                         \
        const char* rA_ = sA0 + (bn) * 16384;                                 \
        const char* rB_ = sB0 + (bn) * 16384;                                 \
        _Pragma("unroll")                                                     \
        for (int i = 0; i < 2; ++i) {                                         \
            const int off = (wr * 32 + i * 16 + m) * 64 + fko;                \
            P##a1h[i] = *(const i32x4*)(rA_ + off);                          \
            P##a1l[i] = *(const i32x4*)(rA_ + 4096  + off);                  \
            P##a2h[i] = *(const i32x4*)(rA_ + 8192  + off);                  \
            P##a2l[i] = *(const i32x4*)(rA_ + 12288 + off);                  \
        }                                                                     \
        _Pragma("unroll")                                                     \
        for (int j = 0; j < 2; ++j) {                                         \
            const int off = (wc * 32 + j * 16 + m) * 64 + fko;                \
            P##b1h[j] = *(const i32x4*)(rB_ + off);                          \
            P##b1l[j] = *(const i32x4*)(rB_ + 4096  + off);                  \
            P##b2h[j] = *(const i32x4*)(rB_ + 8192  + off);                  \
            P##b2l[j] = *(const i32x4*)(rB_ + 12288 + off);                  \
        }                                                                     \
    }

#define DO_MFMA(P)                                                            \
    _Pragma("unroll")                                                         \
    for (int j = 0; j < 2; ++j)                                               \
        _Pragma("unroll")                                                     \
        for (int i = 0; i < 2; ++i) {                                         \
            i32x4 r;                                                          \
            r = rehh[i][j];                                                   \
            r = MFMA_I8(P##a1h[i], P##b1h[j], r, 0, 0, 0);                    \
            r = MFMA_I8(P##a2h[i], P##b2h[j], r, 0, 0, 0);                    \
            rehh[i][j] = r;                                                   \
            r = remx[i][j];                                                   \
            r = MFMA_I8(P##a1h[i], P##b1l[j], r, 0, 0, 0);                    \
            r = MFMA_I8(P##a1l[i], P##b1h[j], r, 0, 0, 0);                    \
            r = MFMA_I8(P##a2h[i], P##b2l[j], r, 0, 0, 0);                    \
            r = MFMA_I8(P##a2l[i], P##b2h[j], r, 0, 0, 0);                    \
            remx[i][j] = r;                                                   \
            r = MFMA_I8(P##a2h[i], P##b1h[j], iphh[i][j], 0, 0, 0);           \
            iphh[i][j] = r;                                                   \
            r = ipmx[i][j];                                                   \
            r = MFMA_I8(P##a2h[i], P##b1l[j], r, 0, 0, 0);                    \
            r = MFMA_I8(P##a2l[i], P##b1h[j], r, 0, 0, 0);                    \
            ipmx[i][j] = r;                                                   \
            r = MFMA_I8(P##a1h[i], P##b2h[j], iqhh[i][j], 0, 0, 0);           \
            iqhh[i][j] = r;                                                   \
            r = iqmx[i][j];                                                   \
            r = MFMA_I8(P##a1h[i], P##b2l[j], r, 0, 0, 0);                    \
            r = MFMA_I8(P##a1l[i], P##b2h[j], r, 0, 0, 0);                    \
            iqmx[i][j] = r;                                                   \
        }

    i32x4 Aa1h[2], Aa1l[2], Aa2h[2], Aa2l[2], Ab1h[2], Ab1l[2], Ab2h[2], Ab2l[2];
    i32x4 Ba1h[2], Ba1l[2], Ba2h[2], Ba2l[2], Bb1h[2], Bb1l[2], Bb2h[2], Bb2l[2];

    // prologue: stage kt0 -> buf0; read kt0 frags; issue kt1 -> buf1
    STAGE(0, 0)
    __syncthreads();
    READ_FRAGS(A, 0)
    STAGE(1, 1)

    for (int it = 0; it < 8; ++it) {
        // ---- A half: compute kt = 2it on regs; fetch kt+1 frags ----------
        __syncthreads();                 // publish buf1 (kt+1); buf0 free
        if (it < 7) STAGE(0, 2 * it + 2) // buf0 <- kt+2
        READ_FRAGS(B, 1)                 // kt+1 frags (overlap with MFMA below)
        __builtin_amdgcn_s_setprio(1);
        DO_MFMA(A)
        __builtin_amdgcn_s_setprio(0);

        // ---- B half: compute kt+1 on regs; fetch kt+2 frags --------------
        __syncthreads();                 // publish buf0 (kt+2); buf1 free
        if (it < 7) {
            STAGE(1, 2 * it + 3)         // buf1 <- kt+3
            READ_FRAGS(A, 0)             // kt+2 frags
        }
        __builtin_amdgcn_s_setprio(1);
        DO_MFMA(B)
        __builtin_amdgcn_s_setprio(0);
    }
#undef STAGE
#undef READ_FRAGS
#undef DO_MFMA

    #pragma unroll
    for (int j = 0; j < 2; ++j) {
        const int col = col0 + wc * 32 + j * 16 + m;
        const float sc = g_scale[col];
        const int c64 = col >> 6;
        #pragma unroll
        for (int i = 0; i < 2; ++i) {
            #pragma unroll
            for (int r = 0; r < 4; ++r) {
                const int row = row0 + wr * 32 + i * 16 + gq * 4 + r;
                const float s2 = g_scale[row] * sc;
                const float re = s2 * (16384.f * (float)rehh[i][j][r] + 128.f * (float)remx[i][j][r]);
                const float im = s2 * (16384.f * (float)(iphh[i][j][r] - iqhh[i][j][r])
                                      + 128.f * (float)(ipmx[i][j][r] - iqmx[i][j][r]));
                const int r64 = row >> 6;
                if (r64 > c64 || row >= col) rho[(size_t)row * D + col] = make_float2(re, im);
                if (r64 == c64 && row > col) rho[(size_t)col * D + row] = make_float2(re, -im);
            }
        }
    }
}

// ---------------------------------------------------------------------------
__global__ void trace_inv(const float2* __restrict__ rho)
{
    __shared__ float red[256];
    float s = 0.f;
    for (int d = threadIdx.x; d < D; d += 256)
        s += rho[(size_t)d * (D + 1)].x;
    red[threadIdx.x] = s;
    __syncthreads();
    for (int off = 128; off > 0; off >>= 1) {
        if (threadIdx.x < off) red[threadIdx.x] += red[threadIdx.x + off];
        __syncthreads();
    }
    if (threadIdx.x == 0) g_inv_tr[0] = 1.0f / red[0];
}

// ---------------------------------------------------------------------------
// 2-qubit staged contraction on a 4x4 register tile (verified r9).
// ---------------------------------------------------------------------------
static __device__ __forceinline__ void qmt2(float2* x,
                                            const float* __restrict__ Mre,
                                            const float* __restrict__ Mim)
{
    float2 y[16];
    #pragma unroll
    for (int sb = 0; sb < 4; ++sb)
        #pragma unroll
        for (int ja = 0; ja < 2; ++ja)
            #pragma unroll
            for (int ia = 0; ia < 2; ++ia) {
                float2 acc = make_float2(0.f, 0.f);
                #pragma unroll
                for (int ib = 0; ib < 2; ++ib)
                    #pragma unroll
                    for (int jb = 0; jb < 2; ++jb) {
                        const float mr = Mre[sb * 4 + ib * 2 + jb];
                        const float mi = Mim[sb * 4 + ib * 2 + jb];
                        const float2 v = x[(ja * 2 + jb) * 4 + ia * 2 + ib];
                        acc.x += mr * v.x - mi * v.y;
                        acc.y += mr * v.y + mi * v.x;
                    }
                y[sb * 4 + ja * 2 + ia] = acc;
            }
    #pragma unroll
    for (int sa = 0; sa < 4; ++sa)
        #pragma unroll
        for (int sb = 0; sb < 4; ++sb) {
            float2 acc = make_float2(0.f, 0.f);
            #pragma unroll
            for (int ia = 0; ia < 2; ++ia)
                #pragma unroll
                for (int ja = 0; ja < 2; ++ja) {
                    const float mr = Mre[sa * 4 + ia * 2 + ja];
                    const float mi = Mim[sa * 4 + ia * 2 + ja];
                    const float2 v = y[sb * 4 + ja * 2 + ia];
                    acc.x += mr * v.x - mi * v.y;
                    acc.y += mr * v.y + mi * v.x;
                }
            x[sa * 4 + sb] = acc;
        }
}

// ---------------------------------------------------------------------------
static __device__ __forceinline__ void pA_pipeline(float2* x, float2* X, const int t,
                                                   const float* __restrict__ mre,
                                                   const float* __restrict__ mim)
{
    qmt2(x, mre, mim);
    #pragma unroll
    for (int d = 0; d < 16; ++d) X[t * 17 + d] = x[d];
    __syncthreads();
    const int a2 = t >> 6, t2 = (t >> 4) & 3, d1 = t & 15;
    #pragma unroll
    for (int j2 = 0; j2 < 4; ++j2)
        #pragma unroll
        for (int i2 = 0; i2 < 4; ++i2)
            x[j2 * 4 + i2] = X[((a2 * 4 + j2) * 16 + t2 * 4 + i2) * 17 + d1];
    __syncthreads();
    qmt2(x, mre, mim);
    #pragma unroll
    for (int d = 0; d < 16; ++d) X[(a2 * 4 + t2) * 257 + d * 16 + d1] = x[d];
    __syncthreads();
    const int e2 = t >> 4, e1 = t & 15;
    #pragma unroll
    for (int j2 = 0; j2 < 4; ++j2)
        #pragma unroll
        for (int i2 = 0; i2 < 4; ++i2)
            x[j2 * 4 + i2] = X[(j2 * 4 + i2) * 257 + e2 * 16 + e1];
    qmt2(x, mre, mim);
}

// ---------------------------------------------------------------------------
// Fused pass A, Hermitian (r10): lower-triangle tiles, 2080 groups.
// ---------------------------------------------------------------------------
__global__ __launch_bounds__(256) void qmt_pAh(const float2* __restrict__ in,
                                               float2* __restrict__ out,
                                               const float* __restrict__ Mre,
                                               const float* __restrict__ Mim)
{
    __shared__ __align__(16) float2 X[256 * 17];   // 34816 B
    const int t = threadIdx.x;
    const int g = blockIdx.x;
    int rr = (int)((sqrtf(8.f * (float)g + 1.f) - 1.f) * 0.5f);
    while (rr * (rr + 1) / 2 > g) --rr;
    while ((rr + 1) * (rr + 2) / 2 <= g) ++rr;
    const int cc = g - rr * (rr + 1) / 2;          // cc <= rr

    const int a4 = t >> 4, t4 = t & 15;
    float2 x0[16], x[16];
    #pragma unroll
    for (int j2 = 0; j2 < 4; ++j2) {
        const float2* p = in + ((size_t)(rr * 64 + a4 * 4 + j2)) * 4096 + cc * 64 + t4 * 4;
        const float4 v0 = ((const float4*)p)[0];
        const float4 v1 = ((const float4*)p)[1];
        x0[j2 * 4 + 0] = make_float2(v0.x, v0.y);
        x0[j2 * 4 + 1] = make_float2(v0.z, v0.w);
        x0[j2 * 4 + 2] = make_float2(v1.x, v1.y);
        x0[j2 * 4 + 3] = make_float2(v1.z, v1.w);
    }

    #pragma unroll
    for (int q = 0; q < 16; ++q) x[q] = x0[q];
    pA_pipeline(x, X, t, Mre, Mim);
    const int e2 = t >> 4, e1 = t & 15;
    const size_t ob0 = (size_t)(rr * 64 + cc) * 4096 + e2 * 16 + e1;
    #pragma unroll
    for (int d = 0; d < 16; ++d) out[ob0 + (size_t)d * 256] = x[d];

    if (rr != cc) {
        __syncthreads();
        #pragma unroll
        for (int q = 0; q < 16; ++q) x[q] = x0[q];
        pA_pipeline(x, X, t, g_mdre, g_mdim);
        const size_t ob1 = (size_t)(cc * 64 + rr) * 4096 + e2 * 16 + e1;
        #pragma unroll
        for (int d = 0; d < 16; ++d)
            out[ob1 + (size_t)d * 256] = make_float2(x[d].x, -x[d].y);
    }
}

// ---------------------------------------------------------------------------
// r12 half-tile 3-qubit contraction (verified round-2/4 WIN). Each thread
// owns the ja = h half; stages c,b local; stage a via __shfl_xor(.,32).
// ---------------------------------------------------------------------------
static __device__ __forceinline__ void qmt_stage_cb_half(float2* x,
                                                         const float* __restrict__ Mre,
                                                         const float* __restrict__ Mim)
{
    #pragma unroll
    for (int jb = 0; jb < 2; ++jb) {
        float2 y[16];
        #pragma unroll
        for (int sc = 0; sc < 4; ++sc)
            #pragma unroll
            for (int ii = 0; ii < 4; ++ii) {
                float2 acc = make_float2(0.f, 0.f);
                #pragma unroll
                for (int ic = 0; ic < 2; ++ic)
                    #pragma unroll
                    for (int jc = 0; jc < 2; ++jc) {
                        const float mr = Mre[sc * 4 + ic * 2 + jc];
                        const float mi = Mim[sc * 4 + ic * 2 + jc];
                        const float2 v = x[jb * 16 + jc * 8 + ii * 2 + ic];
                        acc.x += mr * v.x - mi * v.y;
                        acc.y += mr * v.y + mi * v.x;
                    }
                y[sc * 4 + ii] = acc;
            }
        #pragma unroll
        for (int q = 0; q < 16; ++q) x[jb * 16 + q] = y[q];
    }
    #pragma unroll
    for (int sc = 0; sc < 4; ++sc) {
        float2 z[8];
        #pragma unroll
        for (int sb = 0; sb < 4; ++sb)
            #pragma unroll
            for (int ia = 0; ia < 2; ++ia) {
                float2 acc = make_float2(0.f, 0.f);
                #pragma unroll
                for (int ib = 0; ib < 2; ++ib)
                    #pragma unroll
                    for (int jb = 0; jb < 2; ++jb) {
                        const float mr = Mre[sb * 4 + ib * 2 + jb];
                        const float mi = Mim[sb * 4 + ib * 2 + jb];
                        const float2 v = x[jb * 16 + sc * 4 + ia * 2 + ib];
                        acc.x += mr * v.x - mi * v.y;
                        acc.y += mr * v.y + mi * v.x;
                    }
                z[sb * 2 + ia] = acc;
            }
        #pragma unroll
        for (int sb = 0; sb < 4; ++sb)
            #pragma unroll
            for (int ia = 0; ia < 2; ++ia)
                x[(sb >> 1) * 16 + sc * 4 + ia * 2 + (sb & 1)] = z[sb * 2 + ia];
    }
}

#define STAGE_A_COEFFS                                                        \
    float Are[2][2], Aim[2][2], Bre[2][2], Bim[2][2];                         \
    _Pragma("unroll")                                                         \
    for (int sal = 0; sal < 2; ++sal)                                         \
        _Pragma("unroll")                                                     \
        for (int ia = 0; ia < 2; ++ia) {                                      \
            const int sa = 2 * h + sal;                                       \
            Are[sal][ia] = Mre[sa * 4 + ia * 2 + h];                          \
            Aim[sal][ia] = Mim[sa * 4 + ia * 2 + h];                          \
            Bre[sal][ia] = Mre[sa * 4 + ia * 2 + (1 - h)];                    \
            Bim[sal][ia] = Mim[sa * 4 + ia * 2 + (1 - h)];                    \
        }

// ---------------------------------------------------------------------------
// Pass B (= p3), r12: in [rr(64), cc(64), S(4096)]; out [r3,c3, s3(64), S].
// 2048 blocks x 256 threads; lane pair (l, l^32) shares one (r3,c3,s) tile.
// ---------------------------------------------------------------------------
__global__ __launch_bounds__(256) void qmt_p3(const float2* __restrict__ in,
                                              float2* __restrict__ out,
                                              const float* __restrict__ Mre,
                                              const float* __restrict__ Mim)
{
    const int t = threadIdx.x;
    const int h = (t >> 5) & 1;
    const int idx = blockIdx.x * 4 + (t >> 6);     // [0, 8192)
    const int rc = idx >> 7;                       // [0, 64)
    const int r3 = rc >> 3, c3 = rc & 7;
    const int s = (idx & 127) * 32 + (t & 31);     // [0, 4096)

    float2 x[32];
    #pragma unroll
    for (int jb = 0; jb < 2; ++jb)
        #pragma unroll
        for (int jc = 0; jc < 2; ++jc) {
            const int j3 = 4 * h + 2 * jb + jc;
            #pragma unroll
            for (int i3 = 0; i3 < 8; ++i3)
                x[jb * 16 + jc * 8 + i3] =
                    in[(size_t)((r3 * 8 + j3) * 64 + c3 * 8 + i3) * 4096 + s];
        }

    qmt_stage_cb_half(x, Mre, Mim);

    STAGE_A_COEFFS
    const size_t ob = ((size_t)(r3 * 8 + c3) * 64) * 4096 + s;
    #pragma unroll
    for (int sbH = 0; sbH < 2; ++sbH)
        #pragma unroll
        for (int sc = 0; sc < 4; ++sc)
            #pragma unroll
            for (int sbL = 0; sbL < 2; ++sbL) {
                const int q = sbH * 16 + sc * 4 + sbL;
                const float2 o0 = x[q], o1 = x[q + 2];
                float2 r0, r1;
                r0.x = __shfl_xor(o0.x, 32); r0.y = __shfl_xor(o0.y, 32);
                r1.x = __shfl_xor(o1.x, 32); r1.y = __shfl_xor(o1.y, 32);
                const int sb = sbH * 2 + sbL;
                #pragma unroll
                for (int sal = 0; sal < 2; ++sal) {
                    const float re = Are[sal][0] * o0.x - Aim[sal][0] * o0.y
                                   + Are[sal][1] * o1.x - Aim[sal][1] * o1.y
                                   + Bre[sal][0] * r0.x - Bim[sal][0] * r0.y
                                   + Bre[sal][1] * r1.x - Bim[sal][1] * r1.y;
                    const float im = Are[sal][0] * o0.y + Aim[sal][0] * o0.x
                                   + Are[sal][1] * o1.y + Aim[sal][1] * o1.x
                                   + Bre[sal][0] * r0.y + Bim[sal][0] * r0.x
                                   + Bre[sal][1] * r1.y + Bim[sal][1] * r1.x;
                    const int s3 = (2 * h + sal) * 16 + sb * 4 + sc;
                    out[ob + (size_t)s3 * 4096] = make_float2(re, im);
                }
            }
}

// ---------------------------------------------------------------------------
// Pass C (= p4, MSB triplet), r12: real-only out [s_hi, s3(64), s_lo(32)].
// 2048 blocks x 256 threads.
// ---------------------------------------------------------------------------
__global__ __launch_bounds__(256) void qmt_p4(const float2* __restrict__ in,
                                              float* __restrict__ out,
                                              const float* __restrict__ Mre,
                                              const float* __restrict__ Mim)
{
    const int t = threadIdx.x;
    const int h = (t >> 5) & 1;
    const int s = (blockIdx.x * 4 + (t >> 6)) * 32 + (t & 31);   // [0, 2^18)

    float2 x[32];
    #pragma unroll
    for (int jb = 0; jb < 2; ++jb)
        #pragma unroll
        for (int jc = 0; jc < 2; ++jc) {
            const int j3 = 4 * h + 2 * jb + jc;
            #pragma unroll
            for (int i3 = 0; i3 < 8; ++i3)
                x[jb * 16 + jc * 8 + i3] = in[(size_t)(j3 * 8 + i3) * 262144 + s];
        }

    qmt_stage_cb_half(x, Mre, Mim);

    STAGE_A_COEFFS
    const size_t ob = (size_t)(s >> 5) * 2048 + (s & 31);
    #pragma unroll
    for (int sbH = 0; sbH < 2; ++sbH)
        #pragma unroll
        for (int sc = 0; sc < 4; ++sc)
            #pragma unroll
            for (int sbL = 0; sbL < 2; ++sbL) {
                const int q = sbH * 16 + sc * 4 + sbL;
                const float2 o0 = x[q], o1 = x[q + 2];
                float2 r0, r1;
                r0.x = __shfl_xor(o0.x, 32); r0.y = __shfl_xor(o0.y, 32);
                r1.x = __shfl_xor(o1.x, 32); r1.y = __shfl_xor(o1.y, 32);
                const int sb = sbH * 2 + sbL;
                #pragma unroll
                for (int sal = 0; sal < 2; ++sal) {
                    const float re = Are[sal][0] * o0.x - Aim[sal][0] * o0.y
                                   + Are[sal][1] * o1.x - Aim[sal][1] * o1.y
                                   + Bre[sal][0] * r0.x - Bim[sal][0] * r0.y
                                   + Bre[sal][1] * r1.x - Bim[sal][1] * r1.y;
                    const int s3 = (2 * h + sal) * 16 + sb * 4 + sc;
                    out[ob + (size_t)s3 * 32] = re;
                }
            }
}

// ---------------------------------------------------------------------------
__global__ void gather_idx(const float* __restrict__ P, const int* __restrict__ idxs,
                           float* __restrict__ out, const int n)
{
    const int i = blockIdx.x * 256 + threadIdx.x;
    if (i < n) {
        const int idx = idxs[i];
        const int s = idx & 262143;
        const size_t pos = (size_t)(s >> 5) * 2048 + (size_t)(idx >> 18) * 32 + (s & 31);
        out[i] = P[pos] * g_inv_tr[0];
    }
}

// ---------------------------------------------------------------------------
extern "C" void kernel_launch(void* const* d_in, const int* in_sizes, int n_in,
                              void* d_out, int out_size, void* d_ws, size_t ws_size,
                              hipStream_t stream)
{
    const float* params = (const float*)d_in[0];  // (2, D, RANK) fp32
    const float* Mre    = (const float*)d_in[1];
    const float* Mim    = (const float*)d_in[2];
    const int*   idxs   = (const int*)d_in[3];
    float*       out    = (float*)d_out;

    float* ws = (float*)d_ws;
    float2* A  = (float2*)ws;                 // 134 MB plane
    float2* Bp = (float2*)(ws + 2 * NTOT);    // 134 MB plane
    char* Wh = (char*)Bp;
    char* Wl = Wh + (size_t)D * 2048;

    convert_w_i8<<<1024, 256, 0, stream>>>(params, Mre, Mim, Wh, Wl);
    gemm_rho_i8<<<2080, 256, 0, stream>>>(Wh, Wl, A);
    trace_inv<<<1, 256, 0, stream>>>(A);

    qmt_pAh<<<2080, 256, 0, stream>>>(A, Bp, Mre, Mim);  // 6 LSB qubits, triangle
    qmt_p3<<<2048, 256, 0, stream>>>(Bp, A, Mre, Mim);   // 3 qubits, half-split
    qmt_p4<<<2048, 256, 0, stream>>>(A, (float*)Bp, Mre, Mim);  // 3 qubits, real out

    gather_idx<<<(out_size + 255) / 256, 256, 0, stream>>>((float*)Bp, idxs, out, out_size);
}

// Round 6
// 412.410 us; speedup vs baseline: 1.1369x; 1.1369x over previous
//
#include <hip/hip_runtime.h>

#define D 4096
#define RANK 1024
#define UELEMS 4194304ULL   // D*RANK
#define NTOT 16777216ULL    // 4^12 = D*D
#define QSCALE 16000.0f

typedef __attribute__((ext_vector_type(4))) int i32x4;

__device__ float g_inv_tr[1];
__device__ float g_scale[D];
__device__ float g_mdre[16];   // M-dagger tables: M†[s][i][j] = conj(M[s][j][i])
__device__ float g_mdim[16];

static __device__ __forceinline__ void load_lds16(const void* g, void* l) {
    __builtin_amdgcn_global_load_lds(
        (const __attribute__((address_space(1))) unsigned int*)g,
        (__attribute__((address_space(3))) unsigned int*)l, 16, 0, 0);
}

#define MFMA_I8 __builtin_amdgcn_mfma_i32_16x16x64_i8

// ---------------------------------------------------------------------------
// i8 split quantization of W = [Ur | Ui] with per-row scale (verified r6).
// r16: additionally writes W2 = k-major copy, W2[p][k16][col][16B], p in
// {Ur-hi, Ur-lo, Ui-hi, Ui-lo}. Scattered 16B stores; each 64B line is
// completed by the 4 waves of one block at the same lane -> L2 combines.
// ---------------------------------------------------------------------------
__global__ __launch_bounds__(256) void convert_w_i8(const float* __restrict__ P,
                                                    const float* __restrict__ Mre,
                                                    const float* __restrict__ Mim,
                                                    char* __restrict__ Wh,
                                                    char* __restrict__ Wl,
                                                    char* __restrict__ W2)
{
    if (blockIdx.x == 0 && threadIdx.x < 16) {
        const int s = threadIdx.x >> 2, i = (threadIdx.x >> 1) & 1, j = threadIdx.x & 1;
        g_mdre[threadIdx.x] =  Mre[s * 4 + j * 2 + i];
        g_mdim[threadIdx.x] = -Mim[s * 4 + j * 2 + i];
    }

    const int w = threadIdx.x >> 6, lane = threadIdx.x & 63;
    const int row = blockIdx.x * 4 + w;

    float ur[16], ui[16];
    const float* pr = P + (size_t)row * RANK + lane * 16;
    const float* pi = P + UELEMS + (size_t)row * RANK + lane * 16;
    #pragma unroll
    for (int q = 0; q < 4; ++q) {
        const float4 a = ((const float4*)pr)[q];
        const float4 b = ((const float4*)pi)[q];
        ur[q * 4 + 0] = a.x; ur[q * 4 + 1] = a.y; ur[q * 4 + 2] = a.z; ur[q * 4 + 3] = a.w;
        ui[q * 4 + 0] = b.x; ui[q * 4 + 1] = b.y; ui[q * 4 + 2] = b.z; ui[q * 4 + 3] = b.w;
    }
    float mx = 0.f;
    #pragma unroll
    for (int e = 0; e < 16; ++e)
        mx = fmaxf(mx, fmaxf(fabsf(ur[e]), fabsf(ui[e])));
    #pragma unroll
    for (int off = 1; off < 64; off <<= 1)
        mx = fmaxf(mx, __shfl_xor(mx, off));
    const float inv = mx > 0.f ? QSCALE / mx : 0.f;
    if (lane == 0) g_scale[row] = mx / QSCALE;

    int hr[16], lr[16], hi[16], li[16];
    #pragma unroll
    for (int e = 0; e < 16; ++e) {
        float q = ur[e] * inv;
        float hf = rintf(q * 0.0078125f);
        hr[e] = (int)hf; lr[e] = (int)rintf(q - 128.f * hf);
        q = ui[e] * inv;
        hf = rintf(q * 0.0078125f);
        hi[e] = (int)hf; li[e] = (int)rintf(q - 128.f * hf);
    }
    uint4 phr, plr, phi, pli;
    unsigned* dst[4] = {(unsigned*)&phr, (unsigned*)&plr, (unsigned*)&phi, (unsigned*)&pli};
    #pragma unroll
    for (int q = 0; q < 4; ++q) {
        unsigned a = 0, b = 0, c = 0, d = 0;
        #pragma unroll
        for (int k = 0; k < 4; ++k) {
            const int sh = k * 8;
            a |= (unsigned)(hr[q * 4 + k] & 255) << sh;
            b |= (unsigned)(lr[q * 4 + k] & 255) << sh;
            c |= (unsigned)(hi[q * 4 + k] & 255) << sh;
            d |= (unsigned)(li[q * 4 + k] & 255) << sh;
        }
        dst[0][q] = a; dst[1][q] = b; dst[2][q] = c; dst[3][q] = d;
    }
    const size_t b1 = (size_t)row * 2048 + lane * 16;
    *(uint4*)&Wh[b1] = phr;          *(uint4*)&Wl[b1] = plr;
    *(uint4*)&Wh[b1 + 1024] = phi;   *(uint4*)&Wl[b1 + 1024] = pli;

    // W2: k-major planes of 4 MB each; lane == k16, byte b == k%16.
    const size_t b2 = ((size_t)lane * 4096 + row) * 16;
    *(uint4*)&W2[b2]                = phr;   // p0 = Ur high
    *(uint4*)&W2[b2 + 4194304]      = plr;   // p1 = Ur low
    *(uint4*)&W2[b2 + 8388608]      = phi;   // p2 = Ui high
    *(uint4*)&W2[b2 + 12582912]     = pli;   // p3 = Ui low
}

// ---------------------------------------------------------------------------
// Fused Hermitian GEMM in i8. r16: 64x64 tile, 2 blocks/CU (r14 loop) with
// the B operand read DIRECTLY from the k-major W2 copy (coalesced 16B/lane
// global loads, L2-resident) instead of LDS. r14/r15 post-mortem: the LDS
// pipe (~2050 cy/CU/kt) and MFMA pipe (~1960 cy) were serialized by a convoy
// — all waves issue their ds_reads together after each barrier, so every
// wave's reads finish at the end of the burst. Moving B to the idle vmem/L2
// pipe halves LDS traffic regardless of scheduling. B loads are issued
// BEFORE the A staging each kt, so the compiler's vmcnt wait for B leaves
// the staging loads in flight (FIFO vmcnt semantics). Bytes delivered to the
// MFMAs are identical to r14 (stage/read swizzles cancelled to k-linear).
// ---------------------------------------------------------------------------
__global__ __launch_bounds__(256, 2) void gemm_rho_i8(const char* __restrict__ Wh,
                                                      const char* __restrict__ Wl,
                                                      const char* __restrict__ W2,
                                                      float2* __restrict__ rho)
{
    __shared__ __align__(16) char sA[2][4][64 * 64];   // 32768 B total

    // XCD-chunk swizzle: 2080 = 8 * 260 exactly (bijective).
    const int g0 = blockIdx.x;
    const int g = (g0 & 7) * 260 + (g0 >> 3);

    int bi = (int)((sqrtf(8.f * (float)g + 1.f) - 1.f) * 0.5f);
    while (bi * (bi + 1) / 2 > g) --bi;
    while ((bi + 1) * (bi + 2) / 2 <= g) ++bi;
    const int bj = g - bi * (bi + 1) / 2;
    const int row0 = bi << 6, col0 = bj << 6;

    const int t = threadIdx.x;
    const int lane = t & 63, w = t >> 6;
    const int wr = w >> 1, wc = w & 1;          // 2x2 waves of 32x32

    // A staging: 64 rows x 64 B per plane; thread t covers row t>>2, slot t&3
    const int ra = t >> 2;
    const int kca = (t & 3) ^ ((ra >> 1) & 3);  // xor-swizzled k-slot
    const size_t aoff = (size_t)(row0 + ra) * 2048 + kca * 16;
    const int ldso = t * 16;                    // linear LDS dest within plane

    const int m = lane & 15, gq = lane >> 4;
    const int fko = (gq ^ ((m >> 1) & 3)) * 16;

    // B frag base in W2: lane (gq, m) of wave-col wc reads
    // W2[p][kt*4 + gq][col0 + wc*32 + j*16 + m][0..16)
    const size_t bcol = ((size_t)gq * 4096 + col0 + wc * 32 + m) * 16;

    i32x4 rehh[2][2], remx[2][2], iphh[2][2], ipmx[2][2], iqhh[2][2], iqmx[2][2];
    #pragma unroll
    for (int i = 0; i < 2; ++i)
        #pragma unroll
        for (int j = 0; j < 2; ++j) {
            rehh[i][j] = (i32x4){0, 0, 0, 0}; remx[i][j] = (i32x4){0, 0, 0, 0};
            iphh[i][j] = (i32x4){0, 0, 0, 0}; ipmx[i][j] = (i32x4){0, 0, 0, 0};
            iqhh[i][j] = (i32x4){0, 0, 0, 0}; iqmx[i][j] = (i32x4){0, 0, 0, 0};
        }

    char* const sA0 = &sA[0][0][0];

#define STAGE_A(bn, kt)                                                       \
    {                                                                         \
        const size_t ko_ = (size_t)(kt) * 64;                                 \
        char* dA_ = sA0 + (bn) * 16384;                                       \
        load_lds16(Wh + aoff + ko_,        dA_ + ldso);                       \
        load_lds16(Wl + aoff + ko_,        dA_ + 4096  + ldso);               \
        load_lds16(Wh + aoff + ko_ + 1024, dA_ + 8192  + ldso);               \
        load_lds16(Wl + aoff + ko_ + 1024, dA_ + 12288 + ldso);               \
    }

    // prologue: stage kt=0 into buffer 0
    STAGE_A(0, 0)
    __syncthreads();

    #pragma unroll 2
    for (int kt = 0; kt < 16; ++kt) {
        const int cur = kt & 1;
        const char* sAc = sA0 + cur * 16384;

        // ---- B frags: coalesced global loads from W2 (issued FIRST so the
        // vmcnt wait for them leaves the staging below in flight) ----------
        i32x4 b1h[2], b1l[2], b2h[2], b2l[2];
        {
            const char* pB = W2 + bcol + (size_t)kt * 262144;
            #pragma unroll
            for (int j = 0; j < 2; ++j) {
                b1h[j] = *(const i32x4*)(pB + j * 256);
                b1l[j] = *(const i32x4*)(pB + 4194304  + j * 256);
                b2h[j] = *(const i32x4*)(pB + 8388608  + j * 256);
                b2l[j] = *(const i32x4*)(pB + 12582912 + j * 256);
            }
        }

        // ---- stage next A tile (drained at the end-of-kt barrier) --------
        if (kt < 15) STAGE_A(cur ^ 1, kt + 1)

        // ---- A frags from LDS --------------------------------------------
        i32x4 fa1h[2], fa1l[2], fa2h[2], fa2l[2];
        #pragma unroll
        for (int i = 0; i < 2; ++i) {
            const int off = (wr * 32 + i * 16 + m) * 64 + fko;
            fa1h[i] = *(const i32x4*)(sAc + off);
            fa1l[i] = *(const i32x4*)(sAc + 4096  + off);
            fa2h[i] = *(const i32x4*)(sAc + 8192  + off);
            fa2l[i] = *(const i32x4*)(sAc + 12288 + off);
        }

        __builtin_amdgcn_s_setprio(1);
        #pragma unroll
        for (int j = 0; j < 2; ++j)
            #pragma unroll
            for (int i = 0; i < 2; ++i) {
                i32x4 r;
                r = rehh[i][j];
                r = MFMA_I8(fa1h[i], b1h[j], r, 0, 0, 0);
                r = MFMA_I8(fa2h[i], b2h[j], r, 0, 0, 0);
                rehh[i][j] = r;
                r = remx[i][j];
                r = MFMA_I8(fa1h[i], b1l[j], r, 0, 0, 0);
                r = MFMA_I8(fa1l[i], b1h[j], r, 0, 0, 0);
                r = MFMA_I8(fa2h[i], b2l[j], r, 0, 0, 0);
                r = MFMA_I8(fa2l[i], b2h[j], r, 0, 0, 0);
                remx[i][j] = r;
                r = MFMA_I8(fa2h[i], b1h[j], iphh[i][j], 0, 0, 0);
                iphh[i][j] = r;
                r = ipmx[i][j];
                r = MFMA_I8(fa2h[i], b1l[j], r, 0, 0, 0);
                r = MFMA_I8(fa2l[i], b1h[j], r, 0, 0, 0);
                ipmx[i][j] = r;
                r = MFMA_I8(fa1h[i], b2h[j], iqhh[i][j], 0, 0, 0);
                iqhh[i][j] = r;
                r = iqmx[i][j];
                r = MFMA_I8(fa1h[i], b2l[j], r, 0, 0, 0);
                r = MFMA_I8(fa1l[i], b2h[j], r, 0, 0, 0);
                iqmx[i][j] = r;
            }
        __builtin_amdgcn_s_setprio(0);

        // publishes kt+1 A staging (vmcnt drain) + protects buffer swap
        __syncthreads();
    }
#undef STAGE_A

    #pragma unroll
    for (int j = 0; j < 2; ++j) {
        const int col = col0 + wc * 32 + j * 16 + m;
        const float sc = g_scale[col];
        const int c64 = col >> 6;
        #pragma unroll
        for (int i = 0; i < 2; ++i) {
            #pragma unroll
            for (int r = 0; r < 4; ++r) {
                const int row = row0 + wr * 32 + i * 16 + gq * 4 + r;
                const float s2 = g_scale[row] * sc;
                const float re = s2 * (16384.f * (float)rehh[i][j][r] + 128.f * (float)remx[i][j][r]);
                const float im = s2 * (16384.f * (float)(iphh[i][j][r] - iqhh[i][j][r])
                                      + 128.f * (float)(ipmx[i][j][r] - iqmx[i][j][r]));
                const int r64 = row >> 6;
                if (r64 > c64 || row >= col) rho[(size_t)row * D + col] = make_float2(re, im);
                if (r64 == c64 && row > col) rho[(size_t)col * D + row] = make_float2(re, -im);
            }
        }
    }
}

// ---------------------------------------------------------------------------
__global__ void trace_inv(const float2* __restrict__ rho)
{
    __shared__ float red[256];
    float s = 0.f;
    for (int d = threadIdx.x; d < D; d += 256)
        s += rho[(size_t)d * (D + 1)].x;
    red[threadIdx.x] = s;
    __syncthreads();
    for (int off = 128; off > 0; off >>= 1) {
        if (threadIdx.x < off) red[threadIdx.x] += red[threadIdx.x + off];
        __syncthreads();
    }
    if (threadIdx.x == 0) g_inv_tr[0] = 1.0f / red[0];
}

// ---------------------------------------------------------------------------
// 2-qubit staged contraction on a 4x4 register tile (verified r9).
// ---------------------------------------------------------------------------
static __device__ __forceinline__ void qmt2(float2* x,
                                            const float* __restrict__ Mre,
                                            const float* __restrict__ Mim)
{
    float2 y[16];
    #pragma unroll
    for (int sb = 0; sb < 4; ++sb)
        #pragma unroll
        for (int ja = 0; ja < 2; ++ja)
            #pragma unroll
            for (int ia = 0; ia < 2; ++ia) {
                float2 acc = make_float2(0.f, 0.f);
                #pragma unroll
                for (int ib = 0; ib < 2; ++ib)
                    #pragma unroll
                    for (int jb = 0; jb < 2; ++jb) {
                        const float mr = Mre[sb * 4 + ib * 2 + jb];
                        const float mi = Mim[sb * 4 + ib * 2 + jb];
                        const float2 v = x[(ja * 2 + jb) * 4 + ia * 2 + ib];
                        acc.x += mr * v.x - mi * v.y;
                        acc.y += mr * v.y + mi * v.x;
                    }
                y[sb * 4 + ja * 2 + ia] = acc;
            }
    #pragma unroll
    for (int sa = 0; sa < 4; ++sa)
        #pragma unroll
        for (int sb = 0; sb < 4; ++sb) {
            float2 acc = make_float2(0.f, 0.f);
            #pragma unroll
            for (int ia = 0; ia < 2; ++ia)
                #pragma unroll
                for (int ja = 0; ja < 2; ++ja) {
                    const float mr = Mre[sa * 4 + ia * 2 + ja];
                    const float mi = Mim[sa * 4 + ia * 2 + ja];
                    const float2 v = y[sb * 4 + ja * 2 + ia];
                    acc.x += mr * v.x - mi * v.y;
                    acc.y += mr * v.y + mi * v.x;
                }
            x[sa * 4 + sb] = acc;
        }
}

// ---------------------------------------------------------------------------
static __device__ __forceinline__ void pA_pipeline(float2* x, float2* X, const int t,
                                                   const float* __restrict__ mre,
                                                   const float* __restrict__ mim)
{
    qmt2(x, mre, mim);
    #pragma unroll
    for (int d = 0; d < 16; ++d) X[t * 17 + d] = x[d];
    __syncthreads();
    const int a2 = t >> 6, t2 = (t >> 4) & 3, d1 = t & 15;
    #pragma unroll
    for (int j2 = 0; j2 < 4; ++j2)
        #pragma unroll
        for (int i2 = 0; i2 < 4; ++i2)
            x[j2 * 4 + i2] = X[((a2 * 4 + j2) * 16 + t2 * 4 + i2) * 17 + d1];
    __syncthreads();
    qmt2(x, mre, mim);
    #pragma unroll
    for (int d = 0; d < 16; ++d) X[(a2 * 4 + t2) * 257 + d * 16 + d1] = x[d];
    __syncthreads();
    const int e2 = t >> 4, e1 = t & 15;
    #pragma unroll
    for (int j2 = 0; j2 < 4; ++j2)
        #pragma unroll
        for (int i2 = 0; i2 < 4; ++i2)
            x[j2 * 4 + i2] = X[(j2 * 4 + i2) * 257 + e2 * 16 + e1];
    qmt2(x, mre, mim);
}

// ---------------------------------------------------------------------------
// Fused pass A, Hermitian (r10): lower-triangle tiles, 2080 groups.
// ---------------------------------------------------------------------------
__global__ __launch_bounds__(256) void qmt_pAh(const float2* __restrict__ in,
                                               float2* __restrict__ out,
                                               const float* __restrict__ Mre,
                                               const float* __restrict__ Mim)
{
    __shared__ __align__(16) float2 X[256 * 17];   // 34816 B
    const int t = threadIdx.x;
    const int g = blockIdx.x;
    int rr = (int)((sqrtf(8.f * (float)g + 1.f) - 1.f) * 0.5f);
    while (rr * (rr + 1) / 2 > g) --rr;
    while ((rr + 1) * (rr + 2) / 2 <= g) ++rr;
    const int cc = g - rr * (rr + 1) / 2;          // cc <= rr

    const int a4 = t >> 4, t4 = t & 15;
    float2 x0[16], x[16];
    #pragma unroll
    for (int j2 = 0; j2 < 4; ++j2) {
        const float2* p = in + ((size_t)(rr * 64 + a4 * 4 + j2)) * 4096 + cc * 64 + t4 * 4;
        const float4 v0 = ((const float4*)p)[0];
        const float4 v1 = ((const float4*)p)[1];
        x0[j2 * 4 + 0] = make_float2(v0.x, v0.y);
        x0[j2 * 4 + 1] = make_float2(v0.z, v0.w);
        x0[j2 * 4 + 2] = make_float2(v1.x, v1.y);
        x0[j2 * 4 + 3] = make_float2(v1.z, v1.w);
    }

    #pragma unroll
    for (int q = 0; q < 16; ++q) x[q] = x0[q];
    pA_pipeline(x, X, t, Mre, Mim);
    const int e2 = t >> 4, e1 = t & 15;
    const size_t ob0 = (size_t)(rr * 64 + cc) * 4096 + e2 * 16 + e1;
    #pragma unroll
    for (int d = 0; d < 16; ++d) out[ob0 + (size_t)d * 256] = x[d];

    if (rr != cc) {
        __syncthreads();
        #pragma unroll
        for (int q = 0; q < 16; ++q) x[q] = x0[q];
        pA_pipeline(x, X, t, g_mdre, g_mdim);
        const size_t ob1 = (size_t)(cc * 64 + rr) * 4096 + e2 * 16 + e1;
        #pragma unroll
        for (int d = 0; d < 16; ++d)
            out[ob1 + (size_t)d * 256] = make_float2(x[d].x, -x[d].y);
    }
}

// ---------------------------------------------------------------------------
// r12 half-tile 3-qubit contraction (verified round-2/4 WIN). Each thread
// owns the ja = h half; stages c,b local; stage a via __shfl_xor(.,32).
// ---------------------------------------------------------------------------
static __device__ __forceinline__ void qmt_stage_cb_half(float2* x,
                                                         const float* __restrict__ Mre,
                                                         const float* __restrict__ Mim)
{
    #pragma unroll
    for (int jb = 0; jb < 2; ++jb) {
        float2 y[16];
        #pragma unroll
        for (int sc = 0; sc < 4; ++sc)
            #pragma unroll
            for (int ii = 0; ii < 4; ++ii) {
                float2 acc = make_float2(0.f, 0.f);
                #pragma unroll
                for (int ic = 0; ic < 2; ++ic)
                    #pragma unroll
                    for (int jc = 0; jc < 2; ++jc) {
                        const float mr = Mre[sc * 4 + ic * 2 + jc];
                        const float mi = Mim[sc * 4 + ic * 2 + jc];
                        const float2 v = x[jb * 16 + jc * 8 + ii * 2 + ic];
                        acc.x += mr * v.x - mi * v.y;
                        acc.y += mr * v.y + mi * v.x;
                    }
                y[sc * 4 + ii] = acc;
            }
        #pragma unroll
        for (int q = 0; q < 16; ++q) x[jb * 16 + q] = y[q];
    }
    #pragma unroll
    for (int sc = 0; sc < 4; ++sc) {
        float2 z[8];
        #pragma unroll
        for (int sb = 0; sb < 4; ++sb)
            #pragma unroll
            for (int ia = 0; ia < 2; ++ia) {
                float2 acc = make_float2(0.f, 0.f);
                #pragma unroll
                for (int ib = 0; ib < 2; ++ib)
                    #pragma unroll
                    for (int jb = 0; jb < 2; ++jb) {
                        const float mr = Mre[sb * 4 + ib * 2 + jb];
                        const float mi = Mim[sb * 4 + ib * 2 + jb];
                        const float2 v = x[jb * 16 + sc * 4 + ia * 2 + ib];
                        acc.x += mr * v.x - mi * v.y;
                        acc.y += mr * v.y + mi * v.x;
                    }
                z[sb * 2 + ia] = acc;
            }
        #pragma unroll
        for (int sb = 0; sb < 4; ++sb)
            #pragma unroll
            for (int ia = 0; ia < 2; ++ia)
                x[(sb >> 1) * 16 + sc * 4 + ia * 2 + (sb & 1)] = z[sb * 2 + ia];
    }
}

#define STAGE_A_COEFFS                                                        \
    float Are[2][2], Aim[2][2], Bre[2][2], Bim[2][2];                         \
    _Pragma("unroll")                                                         \
    for (int sal = 0; sal < 2; ++sal)                                         \
        _Pragma("unroll")                                                     \
        for (int ia = 0; ia < 2; ++ia) {                                      \
            const int sa = 2 * h + sal;                                       \
            Are[sal][ia] = Mre[sa * 4 + ia * 2 + h];                          \
            Aim[sal][ia] = Mim[sa * 4 + ia * 2 + h];                          \
            Bre[sal][ia] = Mre[sa * 4 + ia * 2 + (1 - h)];                    \
            Bim[sal][ia] = Mim[sa * 4 + ia * 2 + (1 - h)];                    \
        }

// ---------------------------------------------------------------------------
// Pass B (= p3), r12: in [rr(64), cc(64), S(4096)]; out [r3,c3, s3(64), S].
// 2048 blocks x 256 threads; lane pair (l, l^32) shares one (r3,c3,s) tile.
// ---------------------------------------------------------------------------
__global__ __launch_bounds__(256) void qmt_p3(const float2* __restrict__ in,
                                              float2* __restrict__ out,
                                              const float* __restrict__ Mre,
                                              const float* __restrict__ Mim)
{
    const int t = threadIdx.x;
    const int h = (t >> 5) & 1;
    const int idx = blockIdx.x * 4 + (t >> 6);     // [0, 8192)
    const int rc = idx >> 7;                       // [0, 64)
    const int r3 = rc >> 3, c3 = rc & 7;
    const int s = (idx & 127) * 32 + (t & 31);     // [0, 4096)

    float2 x[32];
    #pragma unroll
    for (int jb = 0; jb < 2; ++jb)
        #pragma unroll
        for (int jc = 0; jc < 2; ++jc) {
            const int j3 = 4 * h + 2 * jb + jc;
            #pragma unroll
            for (int i3 = 0; i3 < 8; ++i3)
                x[jb * 16 + jc * 8 + i3] =
                    in[(size_t)((r3 * 8 + j3) * 64 + c3 * 8 + i3) * 4096 + s];
        }

    qmt_stage_cb_half(x, Mre, Mim);

    STAGE_A_COEFFS
    const size_t ob = ((size_t)(r3 * 8 + c3) * 64) * 4096 + s;
    #pragma unroll
    for (int sbH = 0; sbH < 2; ++sbH)
        #pragma unroll
        for (int sc = 0; sc < 4; ++sc)
            #pragma unroll
            for (int sbL = 0; sbL < 2; ++sbL) {
                const int q = sbH * 16 + sc * 4 + sbL;
                const float2 o0 = x[q], o1 = x[q + 2];
                float2 r0, r1;
                r0.x = __shfl_xor(o0.x, 32); r0.y = __shfl_xor(o0.y, 32);
                r1.x = __shfl_xor(o1.x, 32); r1.y = __shfl_xor(o1.y, 32);
                const int sb = sbH * 2 + sbL;
                #pragma unroll
                for (int sal = 0; sal < 2; ++sal) {
                    const float re = Are[sal][0] * o0.x - Aim[sal][0] * o0.y
                                   + Are[sal][1] * o1.x - Aim[sal][1] * o1.y
                                   + Bre[sal][0] * r0.x - Bim[sal][0] * r0.y
                                   + Bre[sal][1] * r1.x - Bim[sal][1] * r1.y;
                    const float im = Are[sal][0] * o0.y + Aim[sal][0] * o0.x
                                   + Are[sal][1] * o1.y + Aim[sal][1] * o1.x
                                   + Bre[sal][0] * r0.y + Bim[sal][0] * r0.x
                                   + Bre[sal][1] * r1.y + Bim[sal][1] * r1.x;
                    const int s3 = (2 * h + sal) * 16 + sb * 4 + sc;
                    out[ob + (size_t)s3 * 4096] = make_float2(re, im);
                }
            }
}

// ---------------------------------------------------------------------------
// Pass C (= p4, MSB triplet), r12: real-only out [s_hi, s3(64), s_lo(32)].
// 2048 blocks x 256 threads.
// ---------------------------------------------------------------------------
__global__ __launch_bounds__(256) void qmt_p4(const float2* __restrict__ in,
                                              float* __restrict__ out,
                                              const float* __restrict__ Mre,
                                              const float* __restrict__ Mim)
{
    const int t = threadIdx.x;
    const int h = (t >> 5) & 1;
    const int s = (blockIdx.x * 4 + (t >> 6)) * 32 + (t & 31);   // [0, 2^18)

    float2 x[32];
    #pragma unroll
    for (int jb = 0; jb < 2; ++jb)
        #pragma unroll
        for (int jc = 0; jc < 2; ++jc) {
            const int j3 = 4 * h + 2 * jb + jc;
            #pragma unroll
            for (int i3 = 0; i3 < 8; ++i3)
                x[jb * 16 + jc * 8 + i3] = in[(size_t)(j3 * 8 + i3) * 262144 + s];
        }

    qmt_stage_cb_half(x, Mre, Mim);

    STAGE_A_COEFFS
    const size_t ob = (size_t)(s >> 5) * 2048 + (s & 31);
    #pragma unroll
    for (int sbH = 0; sbH < 2; ++sbH)
        #pragma unroll
        for (int sc = 0; sc < 4; ++sc)
            #pragma unroll
            for (int sbL = 0; sbL < 2; ++sbL) {
                const int q = sbH * 16 + sc * 4 + sbL;
                const float2 o0 = x[q], o1 = x[q + 2];
                float2 r0, r1;
                r0.x = __shfl_xor(o0.x, 32); r0.y = __shfl_xor(o0.y, 32);
                r1.x = __shfl_xor(o1.x, 32); r1.y = __shfl_xor(o1.y, 32);
                const int sb = sbH * 2 + sbL;
                #pragma unroll
                for (int sal = 0; sal < 2; ++sal) {
                    const float re = Are[sal][0] * o0.x - Aim[sal][0] * o0.y
                                   + Are[sal][1] * o1.x - Aim[sal][1] * o1.y
                                   + Bre[sal][0] * r0.x - Bim[sal][0] * r0.y
                                   + Bre[sal][1] * r1.x - Bim[sal][1] * r1.y;
                    const int s3 = (2 * h + sal) * 16 + sb * 4 + sc;
                    out[ob + (size_t)s3 * 32] = re;
                }
            }
}

// ---------------------------------------------------------------------------
__global__ void gather_idx(const float* __restrict__ P, const int* __restrict__ idxs,
                           float* __restrict__ out, const int n)
{
    const int i = blockIdx.x * 256 + threadIdx.x;
    if (i < n) {
        const int idx = idxs[i];
        const int s = idx & 262143;
        const size_t pos = (size_t)(s >> 5) * 2048 + (size_t)(idx >> 18) * 32 + (s & 31);
        out[i] = P[pos] * g_inv_tr[0];
    }
}

// ---------------------------------------------------------------------------
extern "C" void kernel_launch(void* const* d_in, const int* in_sizes, int n_in,
                              void* d_out, int out_size, void* d_ws, size_t ws_size,
                              hipStream_t stream)
{
    const float* params = (const float*)d_in[0];  // (2, D, RANK) fp32
    const float* Mre    = (const float*)d_in[1];
    const float* Mim    = (const float*)d_in[2];
    const int*   idxs   = (const int*)d_in[3];
    float*       out    = (float*)d_out;

    float* ws = (float*)d_ws;
    float2* A  = (float2*)ws;                 // 134 MB plane
    float2* Bp = (float2*)(ws + 2 * NTOT);    // 134 MB plane
    char* Wh = (char*)Bp;
    char* Wl = Wh + (size_t)D * 2048;
    char* W2 = Wl + (size_t)D * 2048;         // 16 MB k-major copy

    convert_w_i8<<<1024, 256, 0, stream>>>(params, Mre, Mim, Wh, Wl, W2);
    gemm_rho_i8<<<2080, 256, 0, stream>>>(Wh, Wl, W2, A);
    trace_inv<<<1, 256, 0, stream>>>(A);

    qmt_pAh<<<2080, 256, 0, stream>>>(A, Bp, Mre, Mim);  // 6 LSB qubits, triangle
    qmt_p3<<<2048, 256, 0, stream>>>(Bp, A, Mre, Mim);   // 3 qubits, half-split
    qmt_p4<<<2048, 256, 0, stream>>>(A, (float*)Bp, Mre, Mim);  // 3 qubits, real out

    gather_idx<<<(out_size + 255) / 256, 256, 0, stream>>>((float*)Bp, idxs, out, out_size);
}